// Round 1
// baseline (3995.697 us; speedup 1.0000x reference)
//
#include <hip/hip_runtime.h>

namespace {

constexpr int H  = 64;
constexpr int IN = 21;
constexpr int T  = 3000;
constexpr int B  = 512;
constexpr int G  = 4 * H;   // 256 gates

__device__ __forceinline__ float sigm(float v) {
    return 1.0f / (1.0f + __expf(-v));
}

__launch_bounds__(256, 2)
__global__ void lstm_fused(const float* __restrict__ x,
                           const float* __restrict__ Wih0, const float* __restrict__ Whh0,
                           const float* __restrict__ bih0, const float* __restrict__ bhh0,
                           const float* __restrict__ Wih1, const float* __restrict__ Whh1,
                           const float* __restrict__ bih1, const float* __restrict__ bhh1,
                           const float* __restrict__ Wfc,  const float* __restrict__ bfc,
                           float* __restrict__ out)
{
    const int b   = blockIdx.x;    // one batch element per block
    const int tid = threadIdx.x;   // gate index 0..255

    __shared__ float w0x[IN][G];                 // Wih0^T, conflict-free per-lane reads
    __shared__ __align__(16) float h1s[H];
    __shared__ __align__(16) float h2s[H];
    __shared__ float a0[G];
    __shared__ float a1[G];
    __shared__ __align__(16) float xbuf[2][IN + 3]; // pad to keep float alignment simple

    // ---- stage Wih0 transposed into LDS (once) ----
    for (int idx = tid; idx < IN * G; idx += 256) {
        int g = idx / IN;
        int k = idx - g * IN;
        w0x[k][g] = Wih0[idx];
    }

    // ---- per-thread weight rows in registers: Whh0, Wih1, Whh1 ----
    float w0h[H], w1x[H], w1h[H];
    {
        const float4* p0 = (const float4*)(Whh0 + tid * H);
        const float4* p1 = (const float4*)(Wih1 + tid * H);
        const float4* p2 = (const float4*)(Whh1 + tid * H);
        #pragma unroll
        for (int i = 0; i < H / 4; ++i) {
            float4 v0 = p0[i];
            w0h[4*i+0] = v0.x; w0h[4*i+1] = v0.y; w0h[4*i+2] = v0.z; w0h[4*i+3] = v0.w;
            float4 v1 = p1[i];
            w1x[4*i+0] = v1.x; w1x[4*i+1] = v1.y; w1x[4*i+2] = v1.z; w1x[4*i+3] = v1.w;
            float4 v2 = p2[i];
            w1h[4*i+0] = v2.x; w1h[4*i+1] = v2.y; w1h[4*i+2] = v2.z; w1h[4*i+3] = v2.w;
        }
    }
    const float bias0 = bih0[tid] + bhh0[tid];
    const float bias1 = bih1[tid] + bhh1[tid];

    if (tid < H) { h1s[tid] = 0.0f; h2s[tid] = 0.0f; }
    if (tid < IN) xbuf[0][tid] = x[((size_t)b * T + 0) * IN + tid];
    float c_reg = 0.0f;   // c1 for tid<64 (wave0 lanes), c2 for 64<=tid<128
    __syncthreads();

    // Pipelined loop: iteration t computes gates0(t) || gates1(t-1) in phase A,
    // then pointwise0(t) (wave0) || pointwise1(t-1) (wave1) in phase B.
    for (int t = 0; t < T; ++t) {
        // prefetch next x into the other buffer (written after the FMAs below)
        float xv = 0.0f;
        const bool ldx = (tid < IN) && (t + 1 < T);
        if (ldx) xv = x[((size_t)b * T + (t + 1)) * IN + tid];

        const int p = t & 1;
        float acc0a = bias0, acc0b = 0.0f;
        float acc1a = bias1, acc1b = 0.0f;

        #pragma unroll
        for (int k = 0; k < IN; ++k)
            acc0a = fmaf(w0x[k][tid], xbuf[p][k], acc0a);

        const float4* h1v = (const float4*)h1s;
        const float4* h2v = (const float4*)h2s;
        #pragma unroll
        for (int k4 = 0; k4 < H / 4; ++k4) {
            float4 hv = h1v[k4];
            float4 gv = h2v[k4];
            acc0a = fmaf(w0h[4*k4+0], hv.x, acc0a);
            acc0b = fmaf(w0h[4*k4+1], hv.y, acc0b);
            acc0a = fmaf(w0h[4*k4+2], hv.z, acc0a);
            acc0b = fmaf(w0h[4*k4+3], hv.w, acc0b);
            acc1a = fmaf(w1x[4*k4+0], hv.x, acc1a);
            acc1b = fmaf(w1x[4*k4+1], hv.y, acc1b);
            acc1a = fmaf(w1x[4*k4+2], hv.z, acc1a);
            acc1b = fmaf(w1x[4*k4+3], hv.w, acc1b);
            acc1a = fmaf(w1h[4*k4+0], gv.x, acc1a);
            acc1b = fmaf(w1h[4*k4+1], gv.y, acc1b);
            acc1a = fmaf(w1h[4*k4+2], gv.z, acc1a);
            acc1b = fmaf(w1h[4*k4+3], gv.w, acc1b);
        }
        a0[tid] = acc0a + acc0b;
        a1[tid] = acc1a + acc1b;
        if (ldx) xbuf[p ^ 1][tid] = xv;
        __syncthreads();

        if (tid < H) {
            // layer-0 pointwise for step t
            const int u = tid;
            float ig = sigm(a0[u]);
            float fg = sigm(a0[H + u]);
            float gg = tanhf(a0[2 * H + u]);
            float og = sigm(a0[3 * H + u]);
            c_reg = fmaf(fg, c_reg, ig * gg);
            h1s[u] = og * tanhf(c_reg);
        } else if (tid < 2 * H) {
            // layer-1 pointwise for step t-1 (skip at t==0: h2 stays 0)
            if (t > 0) {
                const int u = tid - H;
                float ig = sigm(a1[u]);
                float fg = sigm(a1[H + u]);
                float gg = tanhf(a1[2 * H + u]);
                float og = sigm(a1[3 * H + u]);
                c_reg = fmaf(fg, c_reg, ig * gg);
                h2s[u] = og * tanhf(c_reg);
            }
        }
        __syncthreads();
    }

    // ---- epilogue: gates1(T-1) + pointwise1(T-1) ----
    {
        float acc1a = bias1, acc1b = 0.0f;
        const float4* h1v = (const float4*)h1s;
        const float4* h2v = (const float4*)h2s;
        #pragma unroll
        for (int k4 = 0; k4 < H / 4; ++k4) {
            float4 hv = h1v[k4];
            float4 gv = h2v[k4];
            acc1a = fmaf(w1x[4*k4+0], hv.x, acc1a);
            acc1b = fmaf(w1x[4*k4+1], hv.y, acc1b);
            acc1a = fmaf(w1x[4*k4+2], hv.z, acc1a);
            acc1b = fmaf(w1x[4*k4+3], hv.w, acc1b);
            acc1a = fmaf(w1h[4*k4+0], gv.x, acc1a);
            acc1b = fmaf(w1h[4*k4+1], gv.y, acc1b);
            acc1a = fmaf(w1h[4*k4+2], gv.z, acc1a);
            acc1b = fmaf(w1h[4*k4+3], gv.w, acc1b);
        }
        a1[tid] = acc1a + acc1b;
    }
    __syncthreads();
    if (tid >= H && tid < 2 * H) {
        const int u = tid - H;
        float ig = sigm(a1[u]);
        float fg = sigm(a1[H + u]);
        float gg = tanhf(a1[2 * H + u]);
        float og = sigm(a1[3 * H + u]);
        c_reg = fmaf(fg, c_reg, ig * gg);
        h2s[u] = og * tanhf(c_reg);
    }
    __syncthreads();

    // ---- final FC: out[b] = dot(h2, Wfc) + bfc ----
    if (tid < H) {
        float v = h2s[tid] * Wfc[tid];
        #pragma unroll
        for (int off = 32; off > 0; off >>= 1)
            v += __shfl_down(v, off, 64);
        if (tid == 0) out[b] = v + bfc[0];
    }
}

} // namespace

extern "C" void kernel_launch(void* const* d_in, const int* in_sizes, int n_in,
                              void* d_out, int out_size, void* d_ws, size_t ws_size,
                              hipStream_t stream)
{
    const float* x    = (const float*)d_in[0];
    const float* Wih0 = (const float*)d_in[1];
    const float* Whh0 = (const float*)d_in[2];
    const float* bih0 = (const float*)d_in[3];
    const float* bhh0 = (const float*)d_in[4];
    const float* Wih1 = (const float*)d_in[5];
    const float* Whh1 = (const float*)d_in[6];
    const float* bih1 = (const float*)d_in[7];
    const float* bhh1 = (const float*)d_in[8];
    const float* Wfc  = (const float*)d_in[9];
    const float* bfc  = (const float*)d_in[10];
    float* out = (float*)d_out;

    hipLaunchKernelGGL(lstm_fused, dim3(B), dim3(256), 0, stream,
                       x, Wih0, Whh0, bih0, bhh0, Wih1, Whh1, bih1, bhh1,
                       Wfc, bfc, out);
}